// Round 5
// baseline (172.245 us; speedup 1.0000x reference)
//
#include <hip/hip_runtime.h>
#include <hip/hip_bf16.h>

#define TB 16384
#define CDIM 512
#define OUTD 512
#define NE 16
#define NE_TOT 17
#define LOSS_SCALE 0.01f
#define BM 128
#define BN 128
#define BK 64
#define MAX_SCHED_P 320
#define MAXFLAG 8192
#define MARGIN 1e-3f

typedef __bf16 bf16_t;
typedef bf16_t bf16x8 __attribute__((ext_vector_type(8)));
typedef float f32x4 __attribute__((ext_vector_type(4)));
typedef unsigned short ushort4_t __attribute__((ext_vector_type(4)));
typedef unsigned short ushort8_t __attribute__((ext_vector_type(8)));

__device__ __forceinline__ unsigned short f2bf(float f) {
    unsigned int u = __float_as_uint(f);
    u += 0x7fffu + ((u >> 16) & 1u);   // round-to-nearest-even
    return (unsigned short)(u >> 16);
}
__device__ __forceinline__ float bf2f(unsigned short h) {
    return __uint_as_float((unsigned int)h << 16);
}

__device__ __forceinline__ void async_copy16(void* lds, const void* g) {
    __builtin_amdgcn_global_load_lds(
        (const __attribute__((address_space(1))) unsigned int*)g,
        (__attribute__((address_space(3))) unsigned int*)lds, 16, 0, 0);
}

// ---------------- prep: init small state + assign_w hi/lo bf16 split ----------------
__global__ __launch_bounds__(256) void k_prep(
    const float* __restrict__ aw, unsigned short* __restrict__ awhl,
    int* pair_cnt, float* importance, int* nflag, int* wflag)
{
    int t = threadIdx.x;
    pair_cnt[t] = 0;
    if (t < NE) importance[t] = 0.f;
    if (t == 0) { *nflag = 0; *wflag = 0; }
    for (int i = t; i < NE * CDIM; i += 256) {
        float f = aw[i];
        unsigned short h = f2bf(f);
        float r = f - bf2f(h);
        awhl[i] = h;
        awhl[NE * CDIM + i] = f2bf(r);
    }
}

// pw_w1 + bias_w -> wbf [17][OUT][C] bf16; also detect bias_w != 0
__global__ void k_wconv(const float* __restrict__ pw, const float* __restrict__ bw,
                        unsigned short* __restrict__ wbf, int* __restrict__ wflag) {
    long i = (long)blockIdx.x * 256 + threadIdx.x;   // float4 index
    const long NPW = (long)NE * OUTD * CDIM / 4;
    const long NTOT = (long)NE_TOT * OUTD * CDIM / 4;
    if (i >= NTOT) return;
    const float* src = (i < NPW) ? (pw + i * 4) : (bw + (i - NPW) * 4);
    float4 v = *(const float4*)src;
    ushort4_t o;
    o[0] = f2bf(v.x); o[1] = f2bf(v.y); o[2] = f2bf(v.z); o[3] = f2bf(v.w);
    *(ushort4_t*)(wbf + i * 4) = o;
    if (i >= NPW && (v.x != 0.f || v.y != 0.f || v.z != 0.f || v.w != 0.f))
        atomicOr(wflag, 1);
}

// ---------------- gating via MFMA hi/lo ----------------
// 4 waves/block, each wave one 16-token x 16-expert tile.
__global__ __launch_bounds__(256) void k_gate(
    const float* __restrict__ x, const unsigned short* __restrict__ awhl,
    const float* __restrict__ ab, unsigned short* __restrict__ xbf,
    int* __restrict__ dec, float2* __restrict__ respd,
    int* __restrict__ flaglist, int* __restrict__ nflag, float* __restrict__ importance)
{
    __shared__ float imp_s[NE];
    int tid = threadIdx.x;
    if (tid < NE) imp_s[tid] = 0.f;
    __syncthreads();

    int wv = tid >> 6, l = tid & 63;
    int n0 = blockIdx.x * 64 + wv * 16;
    int e = l & 15;          // expert (B-frag row / D col); also A-load token row
    int kg = l >> 4;         // k-group

    const float* xrow = x + (size_t)(n0 + e) * CDIM + kg * 8;
    unsigned short* xbrow = xbf + (size_t)(n0 + e) * CDIM + kg * 8;
    const unsigned short* whiP = awhl + e * CDIM + kg * 8;
    const unsigned short* wloP = whiP + NE * CDIM;

    f32x4 acc = (f32x4){0.f, 0.f, 0.f, 0.f};
    #pragma unroll 4
    for (int ks = 0; ks < 16; ++ks) {
        float4 v0 = *(const float4*)(xrow + ks * 32);
        float4 v1 = *(const float4*)(xrow + ks * 32 + 4);
        ushort8_t hx, lx;
        #define CVT(idx, f) { unsigned short h_ = f2bf(f); hx[idx] = h_; \
                              float r_ = (f) - bf2f(h_); lx[idx] = f2bf(r_); }
        CVT(0, v0.x) CVT(1, v0.y) CVT(2, v0.z) CVT(3, v0.w)
        CVT(4, v1.x) CVT(5, v1.y) CVT(6, v1.z) CVT(7, v1.w)
        #undef CVT
        *(ushort8_t*)(xbrow + ks * 32) = hx;
        ushort8_t wh8 = *(const ushort8_t*)(whiP + ks * 32);
        ushort8_t wl8 = *(const ushort8_t*)(wloP + ks * 32);
        bf16x8 ah = *(bf16x8*)&hx, al = *(bf16x8*)&lx;
        bf16x8 bh = *(bf16x8*)&wh8, bl = *(bf16x8*)&wl8;
        acc = __builtin_amdgcn_mfma_f32_16x16x32_bf16(al, bh, acc, 0, 0, 0);
        acc = __builtin_amdgcn_mfma_f32_16x16x32_bf16(ah, bl, acc, 0, 0, 0);
        acc = __builtin_amdgcn_mfma_f32_16x16x32_bf16(ah, bh, acc, 0, 0, 0);
    }
    float bias = ab[e];
    f32x4 E;
    #pragma unroll
    for (int q = 0; q < 4; ++q) E[q] = acc[q] + bias;

    // top-3 butterfly over the 16-lane expert groups, per component
    f32x4 m1 = E, m2, m3;
    #pragma unroll
    for (int q = 0; q < 4; ++q) { m2[q] = -3.4e38f; m3[q] = -3.4e38f; }
    #pragma unroll
    for (int off = 1; off <= 8; off <<= 1) {
        #pragma unroll
        for (int q = 0; q < 4; ++q) {
            float o1 = __shfl_xor(m1[q], off, 64);
            float o2 = __shfl_xor(m2[q], off, 64);
            float o3 = __shfl_xor(m3[q], off, 64);
            float M1 = fmaxf(m1[q], o1), x1 = fminf(m1[q], o1);
            float h2 = fmaxf(m2[q], o2), l2 = fminf(m2[q], o2);
            float M2 = fmaxf(x1, h2), x2 = fminf(x1, h2);
            float M3 = fmaxf(fmaxf(x2, l2), fmaxf(m3[q], o3));
            m1[q] = M1; m2[q] = M2; m3[q] = M3;
        }
    }
    f32x4 p, z;
    #pragma unroll
    for (int q = 0; q < 4; ++q) p[q] = (E[q] >= m2[q]) ? expf(E[q] - m1[q]) : 0.f;
    z = p;
    #pragma unroll
    for (int off = 1; off <= 8; off <<= 1)
        #pragma unroll
        for (int q = 0; q < 4; ++q) z[q] += __shfl_xor(z[q], off, 64);
    f32x4 resp;
    #pragma unroll
    for (int q = 0; q < 4; ++q) resp[q] = p[q] / z[q];

    int grp = l >> 4;
    int elo_q[4], ehi_q[4];
    float rlo_q[4], rhi_q[4];
    #pragma unroll
    for (int q = 0; q < 4; ++q) {
        unsigned long long mq = __ballot(p[q] > 0.f);
        unsigned int sub = (unsigned int)((mq >> (grp * 16)) & 0xffffULL);
        elo_q[q] = __builtin_ctz(sub);
        ehi_q[q] = 31 - __builtin_clz(sub);
        rlo_q[q] = __shfl(resp[q], grp * 16 + elo_q[q], 64);
        rhi_q[q] = __shfl(resp[q], grp * 16 + ehi_q[q], 64);
    }
    if ((l & 15) == 0) {
        #pragma unroll
        for (int q = 0; q < 4; ++q) {
            int n = n0 + grp * 4 + q;
            dec[n] = elo_q[q] | (ehi_q[q] << 8);
            respd[n] = make_float2(rlo_q[q], rhi_q[q]);
            if (m2[q] - m3[q] < MARGIN) {
                int ix = atomicAdd(nflag, 1);
                if (ix < MAXFLAG) flaglist[ix] = n;
            }
        }
    }
    float s = resp[0] + resp[1] + resp[2] + resp[3];
    s += __shfl_xor(s, 16, 64);
    s += __shfl_xor(s, 32, 64);
    if (l < 16) atomicAdd(&imp_s[e], s);
    __syncthreads();
    if (tid < NE) unsafeAtomicAdd(&importance[tid], imp_s[tid]);
}

// ---------------- fp64 repair for ambiguous tokens ----------------
__global__ __launch_bounds__(256) void k_repair(
    const float* __restrict__ x, const float* __restrict__ aw, const float* __restrict__ ab,
    const int* __restrict__ flaglist, const int* __restrict__ nflag,
    int* __restrict__ dec, float2* __restrict__ respd, float* __restrict__ importance)
{
    __shared__ double part[16][17];
    __shared__ double Ed[16];
    int tid = threadIdx.x;
    int e = tid >> 4, p = tid & 15;
    int nf = *nflag; if (nf > MAXFLAG) nf = MAXFLAG;
    for (int fi = blockIdx.x; fi < nf; fi += gridDim.x) {
        int n = flaglist[fi];
        const float* xp = x + (size_t)n * CDIM + p * 32;
        const float* wp = aw + e * CDIM + p * 32;
        double acc = 0.0;
        for (int j = 0; j < 32; ++j) acc = fma((double)xp[j], (double)wp[j], acc);
        part[e][p] = acc;
        __syncthreads();
        if (tid < 16) {
            double s = (double)ab[tid];
            for (int q = 0; q < 16; ++q) s += part[tid][q];
            Ed[tid] = s;
        }
        __syncthreads();
        if (tid == 0) {
            double m1 = -1e300, m2 = -1e300, m3 = -1e300;
            for (int q = 0; q < 16; ++q) {
                double v = Ed[q];
                if (v > m1) { m3 = m2; m2 = m1; m1 = v; }
                else if (v > m2) { m3 = m2; m2 = v; }
                else if (v > m3) { m3 = v; }
            }
            int elo = -1, ehi = -1;
            for (int q = 0; q < 16; ++q)
                if (Ed[q] >= m2) { if (elo < 0) elo = q; else ehi = q; }
            double plo = exp(Ed[elo] - m1), phi = exp(Ed[ehi] - m1);
            double zz = plo + phi;
            float rlo = (float)(plo / zz), rhi = (float)(phi / zz);
            int od = dec[n]; float2 orr = respd[n];
            unsafeAtomicAdd(&importance[od & 0xff], -orr.x);
            unsafeAtomicAdd(&importance[(od >> 8) & 0xff], -orr.y);
            unsafeAtomicAdd(&importance[elo], rlo);
            unsafeAtomicAdd(&importance[ehi], rhi);
            dec[n] = elo | (ehi << 8);
            respd[n] = make_float2(rlo, rhi);
        }
        __syncthreads();
    }
}

// ---------------- pair counting ----------------
__global__ __launch_bounds__(256) void k_count(
    const int* __restrict__ dec, int* __restrict__ pair_cnt)
{
    __shared__ int c_s[256];
    int tid = threadIdx.x;
    c_s[tid] = 0;
    __syncthreads();
    int n = blockIdx.x * 256 + tid;
    int d = dec[n];
    int pid = ((d & 0xff) << 4) | ((d >> 8) & 0xff);
    atomicAdd(&c_s[pid], 1);
    __syncthreads();
    if (c_s[tid] > 0) atomicAdd(&pair_cnt[tid], c_s[tid]);
}

// ---------------- scan + sched + loss ----------------
__global__ void k_scan(const int* __restrict__ pair_cnt, int* __restrict__ pair_base,
                       int* __restrict__ pair_fill, int* __restrict__ sched,
                       int* __restrict__ sn,
                       const float* __restrict__ importance, float* __restrict__ out_loss)
{
    __shared__ int base_s[256];
    int t = threadIdx.x;
    if (t == 0) {
        int p = 0;
        for (int i = 0; i < 256; ++i) { base_s[i] = p; p += pair_cnt[i]; }
    }
    if (t == 1) {
        int ns = 0;
        for (int i = 0; i < 256; ++i) {
            int nb = (pair_cnt[i] + BM - 1) / BM;
            for (int b = 0; b < nb; ++b) sched[ns++] = (i << 8) | b;
        }
        *sn = ns;
    }
    if (t >= 64 && t < 128) {          // loss on wave 1
        int l = t - 64;
        float v = (l < NE) ? importance[l] : 0.f;
        float s = v;
        #pragma unroll
        for (int off = 8; off >= 1; off >>= 1) s += __shfl_xor(s, off, 64);
        float mean = s / 16.f;
        float d = (l < NE) ? (v - mean) : 0.f;
        float ss = d * d;
        #pragma unroll
        for (int off = 8; off >= 1; off >>= 1) ss += __shfl_xor(ss, off, 64);
        if (l == 0) {
            float stdv = sqrtf(ss / 15.f);   // ddof=1
            out_loss[0] = LOSS_SCALE * stdv / mean;
        }
    }
    __syncthreads();
    pair_base[t] = base_s[t];
    pair_fill[t] = base_s[t];
}

// ---------------- scatter tokens into pair-compact index ----------------
__global__ __launch_bounds__(256) void k_scatter(
    const int* __restrict__ dec, int* __restrict__ pair_fill, int* __restrict__ pidx)
{
    int n = blockIdx.x * 256 + threadIdx.x;
    int d = dec[n];
    int pid = ((d & 0xff) << 4) | ((d >> 8) & 0xff);
    int slot = atomicAdd(&pair_fill[pid], 1);
    pidx[slot] = n;
}

// ---------------- pair GEMM: y = r0*E0(x) + r1*E1(x) + bias_b ----------------
// 2-phase double-buffered LDS; 16 stages (8 per expert); single plain store.
__global__ __launch_bounds__(256) void k_gemm_pair(
    const unsigned short* __restrict__ xbf, const unsigned short* __restrict__ wbf,
    const int* __restrict__ pair_cnt, const int* __restrict__ pair_base,
    const int* __restrict__ pidx, const float2* __restrict__ respd,
    const int* __restrict__ sched, const int* __restrict__ sn,
    const float* __restrict__ bias_b, float* __restrict__ y)
{
    if ((int)blockIdx.y >= *sn) return;
    int s = sched[blockIdx.y];
    int pid = s >> 8, mb = s & 0xff;
    int e0 = pid >> 4, e1 = pid & 15;
    int cnt = pair_cnt[pid];
    int m0 = mb * BM;
    const int* my_idx = pidx + pair_base[pid];
    int n0 = blockIdx.x * BN;
    int tid = threadIdx.x;
    int wave = tid >> 6, lane = tid & 63;
    int wm = wave >> 1, wn = wave & 1;
    int fr = lane & 15, fq = lane >> 4;

    __shared__ unsigned short As[2][BM * BK];   // 32 KiB
    __shared__ unsigned short Bs[2][BM * BK];   // 32 KiB

    f32x4 acc0[4][4], acc1[4][4];
    #pragma unroll
    for (int m = 0; m < 4; ++m)
        #pragma unroll
        for (int nn = 0; nn < 4; ++nn) {
            acc0[m][nn] = (f32x4){0.f, 0.f, 0.f, 0.f};
            acc1[m][nn] = (f32x4){0.f, 0.f, 0.f, 0.f};
        }

    // staging geometry: row = c*32 + wave*8 + (lane>>3), 16B chunk (lane&7);
    // source pre-swizzled (chunk ^ row&7) so linear gload_lds dest + swizzled
    // ds_read match (rule #21).
    int srow = wave * 8 + (lane >> 3);
    int cg = lane & 7;
    const unsigned short* aSrc[4];
    size_t bOff[4];
    #pragma unroll
    for (int c = 0; c < 4; ++c) {
        int row = c * 32 + srow;
        int sc = (cg ^ (row & 7)) * 8;
        int rr = m0 + row; if (rr >= cnt) rr = cnt - 1;
        int tok = my_idx[rr];
        aSrc[c] = xbf + (size_t)tok * CDIM + sc;
        bOff[c] = (size_t)(n0 + row) * CDIM + sc;
    }
    const unsigned short* wb0 = wbf + (size_t)e0 * OUTD * CDIM;
    const unsigned short* wb1 = wbf + (size_t)e1 * OUTD * CDIM;

    auto stagef = [&](int buf, const unsigned short* wb, int k0) {
        #pragma unroll
        for (int c = 0; c < 4; ++c) {
            async_copy16(&As[buf][(c * 32 + wave * 8) * BK], aSrc[c] + k0);
            async_copy16(&Bs[buf][(c * 32 + wave * 8) * BK], wb + bOff[c] + k0);
        }
    };
    auto compute = [&](int cb, f32x4 (&acc)[4][4]) {
        #pragma unroll
        for (int ss = 0; ss < 2; ++ss) {
            bf16x8 af[4], bv[4];
            #pragma unroll
            for (int m = 0; m < 4; ++m) {
                int row = wm * 64 + m * 16 + fr;
                int ch = ((ss * 4 + fq) ^ (row & 7)) * 8;
                af[m] = *(const bf16x8*)(&As[cb][row * BK + ch]);
            }
            #pragma unroll
            for (int nn = 0; nn < 4; ++nn) {
                int row = wn * 64 + nn * 16 + fr;
                int ch = ((ss * 4 + fq) ^ (row & 7)) * 8;
                bv[nn] = *(const bf16x8*)(&Bs[cb][row * BK + ch]);
            }
            #pragma unroll
            for (int m = 0; m < 4; ++m)
                #pragma unroll
                for (int nn = 0; nn < 4; ++nn)
                    acc[m][nn] = __builtin_amdgcn_mfma_f32_16x16x32_bf16(af[m], bv[nn], acc[m][nn], 0, 0, 0);
        }
    };

    stagef(0, wb0, 0);
    __syncthreads();                       // drain prologue stage
    int cur = 0;
    // half 0: expert e0 -> acc0 (prefetch crosses into e1's first tile)
    for (int t = 0; t < 8; ++t) {
        if (t < 7) stagef(cur ^ 1, wb0, (t + 1) * BK);
        else       stagef(cur ^ 1, wb1, 0);
        compute(cur, acc0);
        __syncthreads();                   // drains this iter's stage (landed under MFMA)
        cur ^= 1;
    }
    // half 1: expert e1 -> acc1
    for (int t = 0; t < 8; ++t) {
        if (t < 7) stagef(cur ^ 1, wb1, (t + 1) * BK);
        compute(cur, acc1);
        __syncthreads();
        cur ^= 1;
    }

    float bb[4];
    #pragma unroll
    for (int nn = 0; nn < 4; ++nn) bb[nn] = bias_b[n0 + wn * 64 + nn * 16 + fr];
    #pragma unroll
    for (int m = 0; m < 4; ++m)
        #pragma unroll
        for (int q = 0; q < 4; ++q) {
            int r = m0 + wm * 64 + m * 16 + fq * 4 + q;
            if (r < cnt) {
                int tok = my_idx[r];
                float2 rp = respd[tok];
                float* yrow = y + (size_t)tok * OUTD + n0 + wn * 64 + fr;
                #pragma unroll
                for (int nn = 0; nn < 4; ++nn)
                    yrow[nn * 16] = fmaf(rp.x, acc0[m][nn][q],
                                    fmaf(rp.y, acc1[m][nn][q], bb[nn]));
            }
        }
}

// dense bias GEMM (only when bias_w != 0): y += x @ bias_w^T  (slot 16 of wbf)
__global__ __launch_bounds__(256) void k_dense(
    const unsigned short* __restrict__ xbf, const unsigned short* __restrict__ wbf,
    const int* __restrict__ wflag, float* __restrict__ y)
{
    if (*wflag == 0) return;
    int e = NE;
    int m0 = blockIdx.y * BM;
    int n0 = blockIdx.x * BN;
    int tid = threadIdx.x;
    int wave = tid >> 6, lane = tid & 63;
    int wm = wave >> 1, wn = wave & 1;
    int fr = lane & 15, fq = lane >> 4;

    __shared__ unsigned short As[BM * BK];
    __shared__ unsigned short Bs[BM * BK];

    f32x4 acc[4][4];
    #pragma unroll
    for (int m = 0; m < 4; ++m)
        #pragma unroll
        for (int nn = 0; nn < 4; ++nn) acc[m][nn] = (f32x4){0.f, 0.f, 0.f, 0.f};

    int srow = wave * 8 + (lane >> 3);
    int cg = lane & 7;
    const unsigned short* aSrc[4];
    const unsigned short* bSrc[4];
    #pragma unroll
    for (int c = 0; c < 4; ++c) {
        int row = c * 32 + srow;
        int sc = (cg ^ (row & 7)) * 8;
        aSrc[c] = xbf + (size_t)(m0 + row) * CDIM + sc;
        bSrc[c] = wbf + ((size_t)e * OUTD + n0 + row) * CDIM + sc;
    }
    for (int k0 = 0; k0 < CDIM; k0 += BK) {
        __syncthreads();
        #pragma unroll
        for (int c = 0; c < 4; ++c) {
            async_copy16(&As[(c * 32 + wave * 8) * BK], aSrc[c] + k0);
            async_copy16(&Bs[(c * 32 + wave * 8) * BK], bSrc[c] + k0);
        }
        __syncthreads();
        #pragma unroll
        for (int ss = 0; ss < 2; ++ss) {
            bf16x8 af[4], bv[4];
            #pragma unroll
            for (int m = 0; m < 4; ++m) {
                int row = wm * 64 + m * 16 + fr;
                int ch = ((ss * 4 + fq) ^ (row & 7)) * 8;
                af[m] = *(const bf16x8*)(&As[row * BK + ch]);
            }
            #pragma unroll
            for (int nn = 0; nn < 4; ++nn) {
                int row = wn * 64 + nn * 16 + fr;
                int ch = ((ss * 4 + fq) ^ (row & 7)) * 8;
                bv[nn] = *(const bf16x8*)(&Bs[row * BK + ch]);
            }
            #pragma unroll
            for (int m = 0; m < 4; ++m)
                #pragma unroll
                for (int nn = 0; nn < 4; ++nn)
                    acc[m][nn] = __builtin_amdgcn_mfma_f32_16x16x32_bf16(af[m], bv[nn], acc[m][nn], 0, 0, 0);
        }
    }
    #pragma unroll
    for (int m = 0; m < 4; ++m)
        #pragma unroll
        for (int q = 0; q < 4; ++q) {
            int r = m0 + wm * 64 + m * 16 + fq * 4 + q;
            float* yrow = y + (size_t)r * OUTD + n0 + wn * 64 + fr;
            #pragma unroll
            for (int nn = 0; nn < 4; ++nn) yrow[nn * 16] += acc[m][nn][q];
        }
}

extern "C" void kernel_launch(void* const* d_in, const int* in_sizes, int n_in,
                              void* d_out, int out_size, void* d_ws, size_t ws_size,
                              hipStream_t stream) {
    const float* x        = (const float*)d_in[0];
    const float* assign_w = (const float*)d_in[1];
    const float* assign_b = (const float*)d_in[2];
    const float* pw_w1    = (const float*)d_in[3];
    const float* bias_w   = (const float*)d_in[4];
    const float* bias_b   = (const float*)d_in[5];
    float* y    = (float*)d_out;                 // [TB*OUTD]
    float* loss = y + (size_t)TB * OUTD;         // [1]

    char* ws = (char*)d_ws;
    unsigned short* xbf  = (unsigned short*)(ws);                 // 16,777,216 B
    unsigned short* wbf  = (unsigned short*)(ws + 16777216);      //  8,912,896 B
    int*    pidx      = (int*)   (ws + 25690112);                 //     65,536 B
    int*    dec       = (int*)   (ws + 27787264);                 //     65,536 B
    float2* respd     = (float2*)(ws + 27852800);                 //    131,072 B
    int*    flaglist  = (int*)   (ws + 27983872);                 //     32,768 B
    unsigned short* awhl = (unsigned short*)(ws + 28016640);      //     32,768 B
    char*   misc      = ws + 28049408;
    int*    pair_cnt  = (int*)   (misc + 0);                      // 256 ints
    int*    pair_base = (int*)   (misc + 1024);
    int*    pair_fill = (int*)   (misc + 2048);
    float*  importance= (float*) (misc + 3072);
    int*    nflag     = (int*)   (misc + 3136);
    int*    wflag     = (int*)   (misc + 3140);
    int*    sn        = (int*)   (misc + 3144);
    int*    sched     = (int*)   (misc + 3200);                   // MAX_SCHED_P ints

    k_prep<<<1, 256, 0, stream>>>(assign_w, awhl, pair_cnt, importance, nflag, wflag);
    k_wconv<<<(NE_TOT * OUTD * CDIM / 4 + 255) / 256, 256, 0, stream>>>(pw_w1, bias_w, wbf, wflag);
    k_gate<<<TB / 64, 256, 0, stream>>>(x, awhl, assign_b, xbf, dec, respd,
                                        flaglist, nflag, importance);
    k_repair<<<32, 256, 0, stream>>>(x, assign_w, assign_b, flaglist, nflag,
                                     dec, respd, importance);
    k_count<<<TB / 256, 256, 0, stream>>>(dec, pair_cnt);
    k_scan<<<1, 256, 0, stream>>>(pair_cnt, pair_base, pair_fill, sched, sn,
                                  importance, loss);
    k_scatter<<<TB / 256, 256, 0, stream>>>(dec, pair_fill, pidx);
    k_gemm_pair<<<dim3(OUTD / BN, MAX_SCHED_P), 256, 0, stream>>>(
        xbf, wbf, pair_cnt, pair_base, pidx, respd, sched, sn, bias_b, y);
    k_dense<<<dim3(OUTD / BN, TB / BM), 256, 0, stream>>>(xbf, wbf, wflag, y);
}

// Round 6
// 142.353 us; speedup vs baseline: 1.2100x; 1.2100x over previous
//
#include <hip/hip_runtime.h>
#include <hip/hip_bf16.h>

#define TB 16384
#define CDIM 512
#define OUTD 512
#define NE 16
#define NE_TOT 17
#define LOSS_SCALE 0.01f
#define BM 128
#define BN 64
#define BK 64
#define MAX_SCHED 144
#define MAXFLAG 8192
#define MARGIN 1e-3f

typedef __bf16 bf16_t;
typedef bf16_t bf16x8 __attribute__((ext_vector_type(8)));
typedef float f32x4 __attribute__((ext_vector_type(4)));
typedef unsigned short ushort4_t __attribute__((ext_vector_type(4)));
typedef unsigned short ushort8_t __attribute__((ext_vector_type(8)));

__device__ __forceinline__ unsigned short f2bf(float f) {
    unsigned int u = __float_as_uint(f);
    u += 0x7fffu + ((u >> 16) & 1u);   // round-to-nearest-even
    return (unsigned short)(u >> 16);
}
__device__ __forceinline__ float bf2f(unsigned short h) {
    return __uint_as_float((unsigned int)h << 16);
}

__device__ __forceinline__ void async_copy16(void* lds, const void* g) {
    __builtin_amdgcn_global_load_lds(
        (const __attribute__((address_space(1))) unsigned int*)g,
        (__attribute__((address_space(3))) unsigned int*)lds, 16, 0, 0);
}

// ---------------- prep: init small state + assign_w hi/lo bf16 split ----------------
__global__ __launch_bounds__(256) void k_prep(
    const float* __restrict__ aw, unsigned short* __restrict__ awhl,
    int* cnt0, int* cnt1, float* importance, int* nflag, int* wflag)
{
    int t = threadIdx.x;
    if (t < NE) { cnt0[t] = 0; cnt1[t] = 0; importance[t] = 0.f; }
    if (t == 0) { *nflag = 0; *wflag = 0; }
    for (int i = t; i < NE * CDIM; i += 256) {
        float f = aw[i];
        unsigned short h = f2bf(f);
        float r = f - bf2f(h);
        awhl[i] = h;
        awhl[NE * CDIM + i] = f2bf(r);
    }
}

// pw_w1 + bias_w -> wbf [17][OUT][C] bf16; also detect bias_w != 0
__global__ void k_wconv(const float* __restrict__ pw, const float* __restrict__ bw,
                        unsigned short* __restrict__ wbf, int* __restrict__ wflag) {
    long i = (long)blockIdx.x * 256 + threadIdx.x;   // float4 index
    const long NPW = (long)NE * OUTD * CDIM / 4;
    const long NTOT = (long)NE_TOT * OUTD * CDIM / 4;
    if (i >= NTOT) return;
    const float* src = (i < NPW) ? (pw + i * 4) : (bw + (i - NPW) * 4);
    float4 v = *(const float4*)src;
    ushort4_t o;
    o[0] = f2bf(v.x); o[1] = f2bf(v.y); o[2] = f2bf(v.z); o[3] = f2bf(v.w);
    *(ushort4_t*)(wbf + i * 4) = o;
    if (i >= NPW && (v.x != 0.f || v.y != 0.f || v.z != 0.f || v.w != 0.f))
        atomicOr(wflag, 1);
}

// ---------------- gating via MFMA hi/lo ----------------
// 4 waves/block, each wave one 16-token x 16-expert tile.
__global__ __launch_bounds__(256) void k_gate(
    const float* __restrict__ x, const unsigned short* __restrict__ awhl,
    const float* __restrict__ ab, unsigned short* __restrict__ xbf,
    int* __restrict__ dec, float2* __restrict__ respd,
    int* __restrict__ flaglist, int* __restrict__ nflag, float* __restrict__ importance)
{
    __shared__ float imp_s[NE];
    int tid = threadIdx.x;
    if (tid < NE) imp_s[tid] = 0.f;
    __syncthreads();

    int wv = tid >> 6, l = tid & 63;
    int n0 = blockIdx.x * 64 + wv * 16;
    int e = l & 15;          // expert (B-frag row / D col); also A-load token row
    int kg = l >> 4;         // k-group

    const float* xrow = x + (size_t)(n0 + e) * CDIM + kg * 8;
    unsigned short* xbrow = xbf + (size_t)(n0 + e) * CDIM + kg * 8;
    const unsigned short* whiP = awhl + e * CDIM + kg * 8;
    const unsigned short* wloP = whiP + NE * CDIM;

    f32x4 acc = (f32x4){0.f, 0.f, 0.f, 0.f};
    #pragma unroll 4
    for (int ks = 0; ks < 16; ++ks) {
        float4 v0 = *(const float4*)(xrow + ks * 32);
        float4 v1 = *(const float4*)(xrow + ks * 32 + 4);
        ushort8_t hx, lx;
        #define CVT(idx, f) { unsigned short h_ = f2bf(f); hx[idx] = h_; \
                              float r_ = (f) - bf2f(h_); lx[idx] = f2bf(r_); }
        CVT(0, v0.x) CVT(1, v0.y) CVT(2, v0.z) CVT(3, v0.w)
        CVT(4, v1.x) CVT(5, v1.y) CVT(6, v1.z) CVT(7, v1.w)
        #undef CVT
        *(ushort8_t*)(xbrow + ks * 32) = hx;
        ushort8_t wh8 = *(const ushort8_t*)(whiP + ks * 32);
        ushort8_t wl8 = *(const ushort8_t*)(wloP + ks * 32);
        bf16x8 ah = *(bf16x8*)&hx, al = *(bf16x8*)&lx;
        bf16x8 bh = *(bf16x8*)&wh8, bl = *(bf16x8*)&wl8;
        acc = __builtin_amdgcn_mfma_f32_16x16x32_bf16(al, bh, acc, 0, 0, 0);
        acc = __builtin_amdgcn_mfma_f32_16x16x32_bf16(ah, bl, acc, 0, 0, 0);
        acc = __builtin_amdgcn_mfma_f32_16x16x32_bf16(ah, bh, acc, 0, 0, 0);
    }
    float bias = ab[e];
    f32x4 E;
    #pragma unroll
    for (int q = 0; q < 4; ++q) E[q] = acc[q] + bias;

    // top-3 butterfly over the 16-lane expert groups, per component
    f32x4 m1 = E, m2, m3;
    #pragma unroll
    for (int q = 0; q < 4; ++q) { m2[q] = -3.4e38f; m3[q] = -3.4e38f; }
    #pragma unroll
    for (int off = 1; off <= 8; off <<= 1) {
        #pragma unroll
        for (int q = 0; q < 4; ++q) {
            float o1 = __shfl_xor(m1[q], off, 64);
            float o2 = __shfl_xor(m2[q], off, 64);
            float o3 = __shfl_xor(m3[q], off, 64);
            float M1 = fmaxf(m1[q], o1), x1 = fminf(m1[q], o1);
            float h2 = fmaxf(m2[q], o2), l2 = fminf(m2[q], o2);
            float M2 = fmaxf(x1, h2), x2 = fminf(x1, h2);
            float M3 = fmaxf(fmaxf(x2, l2), fmaxf(m3[q], o3));
            m1[q] = M1; m2[q] = M2; m3[q] = M3;
        }
    }
    f32x4 p, z;
    #pragma unroll
    for (int q = 0; q < 4; ++q) p[q] = (E[q] >= m2[q]) ? expf(E[q] - m1[q]) : 0.f;
    z = p;
    #pragma unroll
    for (int off = 1; off <= 8; off <<= 1)
        #pragma unroll
        for (int q = 0; q < 4; ++q) z[q] += __shfl_xor(z[q], off, 64);
    f32x4 resp;
    #pragma unroll
    for (int q = 0; q < 4; ++q) resp[q] = p[q] / z[q];

    int grp = l >> 4;
    int elo_q[4], ehi_q[4];
    float rlo_q[4], rhi_q[4];
    #pragma unroll
    for (int q = 0; q < 4; ++q) {
        unsigned long long mq = __ballot(p[q] > 0.f);
        unsigned int sub = (unsigned int)((mq >> (grp * 16)) & 0xffffULL);
        elo_q[q] = __builtin_ctz(sub);
        ehi_q[q] = 31 - __builtin_clz(sub);
        rlo_q[q] = __shfl(resp[q], grp * 16 + elo_q[q], 64);
        rhi_q[q] = __shfl(resp[q], grp * 16 + ehi_q[q], 64);
    }
    if ((l & 15) == 0) {
        #pragma unroll
        for (int q = 0; q < 4; ++q) {
            int n = n0 + grp * 4 + q;
            dec[n] = elo_q[q] | (ehi_q[q] << 8);
            respd[n] = make_float2(rlo_q[q], rhi_q[q]);
            if (m2[q] - m3[q] < MARGIN) {
                int ix = atomicAdd(nflag, 1);
                if (ix < MAXFLAG) flaglist[ix] = n;
            }
        }
    }
    float s = resp[0] + resp[1] + resp[2] + resp[3];
    s += __shfl_xor(s, 16, 64);
    s += __shfl_xor(s, 32, 64);
    if (l < 16) atomicAdd(&imp_s[e], s);
    __syncthreads();
    if (tid < NE) unsafeAtomicAdd(&importance[tid], imp_s[tid]);
}

// ---------------- fp64 repair for ambiguous tokens ----------------
__global__ __launch_bounds__(256) void k_repair(
    const float* __restrict__ x, const float* __restrict__ aw, const float* __restrict__ ab,
    const int* __restrict__ flaglist, const int* __restrict__ nflag,
    int* __restrict__ dec, float2* __restrict__ respd, float* __restrict__ importance)
{
    __shared__ double part[16][17];
    __shared__ double Ed[16];
    int tid = threadIdx.x;
    int e = tid >> 4, p = tid & 15;
    int nf = *nflag; if (nf > MAXFLAG) nf = MAXFLAG;
    for (int fi = blockIdx.x; fi < nf; fi += gridDim.x) {
        int n = flaglist[fi];
        const float* xp = x + (size_t)n * CDIM + p * 32;
        const float* wp = aw + e * CDIM + p * 32;
        double acc = 0.0;
        for (int j = 0; j < 32; ++j) acc = fma((double)xp[j], (double)wp[j], acc);
        part[e][p] = acc;
        __syncthreads();
        if (tid < 16) {
            double s = (double)ab[tid];
            for (int q = 0; q < 16; ++q) s += part[tid][q];
            Ed[tid] = s;
        }
        __syncthreads();
        if (tid == 0) {
            double m1 = -1e300, m2 = -1e300, m3 = -1e300;
            for (int q = 0; q < 16; ++q) {
                double v = Ed[q];
                if (v > m1) { m3 = m2; m2 = m1; m1 = v; }
                else if (v > m2) { m3 = m2; m2 = v; }
                else if (v > m3) { m3 = v; }
            }
            int elo = -1, ehi = -1;
            for (int q = 0; q < 16; ++q)
                if (Ed[q] >= m2) { if (elo < 0) elo = q; else ehi = q; }
            double plo = exp(Ed[elo] - m1), phi = exp(Ed[ehi] - m1);
            double zz = plo + phi;
            float rlo = (float)(plo / zz), rhi = (float)(phi / zz);
            int od = dec[n]; float2 orr = respd[n];
            unsafeAtomicAdd(&importance[od & 0xff], -orr.x);
            unsafeAtomicAdd(&importance[(od >> 8) & 0xff], -orr.y);
            unsafeAtomicAdd(&importance[elo], rlo);
            unsafeAtomicAdd(&importance[ehi], rhi);
            dec[n] = elo | (ehi << 8);
            respd[n] = make_float2(rlo, rhi);
        }
        __syncthreads();
    }
}

// ---------------- rank-list building ----------------
__global__ __launch_bounds__(256) void k_build(
    const int* __restrict__ dec, int* __restrict__ cnt0, int* __restrict__ cnt1,
    int* __restrict__ idx0, int* __restrict__ idx1)
{
    __shared__ int l0[NE], l1[NE], b0[NE], b1[NE];
    int tid = threadIdx.x;
    if (tid < NE) { l0[tid] = 0; l1[tid] = 0; }
    __syncthreads();
    int n = blockIdx.x * 256 + tid;
    int d = dec[n];
    int elo = d & 0xff, ehi = (d >> 8) & 0xff;
    int p0 = atomicAdd(&l0[elo], 1);
    int p1 = atomicAdd(&l1[ehi], 1);
    __syncthreads();
    if (tid < NE) {
        b0[tid] = atomicAdd(&cnt0[tid], l0[tid]);
        b1[tid] = atomicAdd(&cnt1[tid], l1[tid]);
    }
    __syncthreads();
    idx0[elo * TB + b0[elo] + p0] = n;
    idx1[ehi * TB + b1[ehi] + p1] = n;
}

// ---------------- loss + schedule (fused tail) ----------------
__global__ void k_finish(const float* __restrict__ importance, float* __restrict__ out_loss,
                         const int* __restrict__ cnt0, const int* __restrict__ cnt1,
                         int* __restrict__ sched0, int* __restrict__ sched1,
                         int* __restrict__ sn0, int* __restrict__ sn1) {
    int l = threadIdx.x;
    if (l < 64) {
        float v = (l < NE) ? importance[l] : 0.f;
        float s = v;
        #pragma unroll
        for (int off = 8; off >= 1; off >>= 1) s += __shfl_xor(s, off, 64);
        float mean = s / 16.f;
        float d = (l < NE) ? (v - mean) : 0.f;
        float ss = d * d;
        #pragma unroll
        for (int off = 8; off >= 1; off >>= 1) ss += __shfl_xor(ss, off, 64);
        if (l == 0) {
            float stdv = sqrtf(ss / 15.f);   // ddof=1
            out_loss[0] = LOSS_SCALE * stdv / mean;
        }
    } else if (l == 64) {
        int p = 0;
        for (int e = 0; e < NE; ++e) {
            int nb = (cnt0[e] + BM - 1) / BM;
            for (int i = 0; i < nb; ++i) sched0[p++] = (e << 16) | i;
        }
        *sn0 = p;
    } else if (l == 65) {
        int p = 0;
        for (int e = 0; e < NE; ++e) {
            int nb = (cnt1[e] + BM - 1) / BM;
            for (int i = 0; i < nb; ++i) sched1[p++] = (e << 16) | i;
        }
        *sn1 = p;
    }
}

// ---------------- rank GEMMs: BM=128 x BN=64, BK=64, 2-phase dbuf LDS ----------------
// 4 waves, each computes a 64x32 output tile (acc[4][2]); plain stores / RMW.
template<int RANK>
__global__ __launch_bounds__(256) void k_gemm(
    const unsigned short* __restrict__ xbf, const unsigned short* __restrict__ wbf,
    const int* __restrict__ cnts, const int* __restrict__ idx,
    const float2* __restrict__ respd, const int* __restrict__ sched,
    const int* __restrict__ sn, const float* __restrict__ bias_b, float* __restrict__ y)
{
    if ((int)blockIdx.y >= *sn) return;
    int s = sched[blockIdx.y];
    int e = s >> 16, m0 = (s & 0xffff) * BM, cnt = cnts[e];
    int n0 = blockIdx.x * BN;
    int tid = threadIdx.x;
    int wave = tid >> 6, lane = tid & 63;
    int wm = wave >> 1, wn = wave & 1;
    int fr = lane & 15, fq = lane >> 4;

    __shared__ unsigned short As[2][BM * BK];   // 32 KiB
    __shared__ unsigned short Bs[2][BN * BK];   // 16 KiB

    const int* my_idx = idx + e * TB;

    f32x4 acc[4][2];
    #pragma unroll
    for (int m = 0; m < 4; ++m)
        #pragma unroll
        for (int nn = 0; nn < 2; ++nn) acc[m][nn] = (f32x4){0.f, 0.f, 0.f, 0.f};

    // staging geometry: row = c*32 + wave*8 + (lane>>3), 16B chunk cg=lane&7;
    // source pre-swizzled (chunk ^ row&7) so linear gload_lds dest + swizzled
    // ds_read match (rule #21).
    int srow = wave * 8 + (lane >> 3);
    int cg = lane & 7;
    const unsigned short* aSrc[4];
    const unsigned short* bSrc[2];
    #pragma unroll
    for (int c = 0; c < 4; ++c) {
        int row = c * 32 + srow;
        int sc = (cg ^ (row & 7)) * 8;
        int rr = m0 + row; if (rr >= cnt) rr = cnt - 1;
        int tok = my_idx[rr];
        aSrc[c] = xbf + (size_t)tok * CDIM + sc;
    }
    #pragma unroll
    for (int c = 0; c < 2; ++c) {
        int row = c * 32 + srow;
        int sc = (cg ^ (row & 7)) * 8;
        bSrc[c] = wbf + ((size_t)e * OUTD + n0 + row) * CDIM + sc;
    }

    auto stagef = [&](int buf, int k0) {
        #pragma unroll
        for (int c = 0; c < 4; ++c)
            async_copy16(&As[buf][(c * 32 + wave * 8) * BK], aSrc[c] + k0);
        #pragma unroll
        for (int c = 0; c < 2; ++c)
            async_copy16(&Bs[buf][(c * 32 + wave * 8) * BK], bSrc[c] + k0);
    };
    auto compute = [&](int cb) {
        #pragma unroll
        for (int ss = 0; ss < 2; ++ss) {
            bf16x8 af[4], bv[2];
            #pragma unroll
            for (int m = 0; m < 4; ++m) {
                int row = wm * 64 + m * 16 + fr;
                int ch = ((ss * 4 + fq) ^ (row & 7)) * 8;
                af[m] = *(const bf16x8*)(&As[cb][row * BK + ch]);
            }
            #pragma unroll
            for (int nn = 0; nn < 2; ++nn) {
                int row = wn * 32 + nn * 16 + fr;
                int ch = ((ss * 4 + fq) ^ (row & 7)) * 8;
                bv[nn] = *(const bf16x8*)(&Bs[cb][row * BK + ch]);
            }
            #pragma unroll
            for (int m = 0; m < 4; ++m)
                #pragma unroll
                for (int nn = 0; nn < 2; ++nn)
                    acc[m][nn] = __builtin_amdgcn_mfma_f32_16x16x32_bf16(af[m], bv[nn], acc[m][nn], 0, 0, 0);
        }
    };

    stagef(0, 0);
    __syncthreads();                      // prologue stage drained
    int cur = 0;
    #pragma unroll
    for (int t = 0; t < 8; ++t) {
        if (t < 7) stagef(cur ^ 1, (t + 1) * BK);   // prefetch next K-tile
        compute(cur);
        __syncthreads();                  // drains this iter's stage (landed under MFMA)
        cur ^= 1;
    }

    float bb[2];
    if (RANK == 0) {
        #pragma unroll
        for (int nn = 0; nn < 2; ++nn) bb[nn] = bias_b[n0 + wn * 32 + nn * 16 + fr];
    }
    #pragma unroll
    for (int m = 0; m < 4; ++m)
        #pragma unroll
        for (int q = 0; q < 4; ++q) {
            int r = m0 + wm * 64 + m * 16 + fq * 4 + q;
            if (r < cnt) {
                int tok = my_idx[r];
                float2 rp = respd[tok];
                float w = (RANK == 0) ? rp.x : rp.y;
                float* yrow = y + (size_t)tok * OUTD + n0 + wn * 32 + fr;
                #pragma unroll
                for (int nn = 0; nn < 2; ++nn) {
                    if (RANK == 0) yrow[nn * 16] = fmaf(w, acc[m][nn][q], bb[nn]);
                    else           yrow[nn * 16] += w * acc[m][nn][q];
                }
            }
        }
}

// dense bias GEMM (only when bias_w != 0): y += x @ bias_w^T  (slot 16 of wbf)
__global__ __launch_bounds__(256) void k_dense(
    const unsigned short* __restrict__ xbf, const unsigned short* __restrict__ wbf,
    const int* __restrict__ wflag, float* __restrict__ y)
{
    if (*wflag == 0) return;
    int e = NE;
    int m0 = blockIdx.y * BM;
    int n0 = blockIdx.x * BN;
    int tid = threadIdx.x;
    int wave = tid >> 6, lane = tid & 63;
    int wm = wave >> 1, wn = wave & 1;
    int fr = lane & 15, fq = lane >> 4;

    __shared__ unsigned short As[2][BM * BK];
    __shared__ unsigned short Bs[2][BN * BK];

    f32x4 acc[4][2];
    #pragma unroll
    for (int m = 0; m < 4; ++m)
        #pragma unroll
        for (int nn = 0; nn < 2; ++nn) acc[m][nn] = (f32x4){0.f, 0.f, 0.f, 0.f};

    int srow = wave * 8 + (lane >> 3);
    int cg = lane & 7;
    const unsigned short* aSrc[4];
    const unsigned short* bSrc[2];
    #pragma unroll
    for (int c = 0; c < 4; ++c) {
        int row = c * 32 + srow;
        int sc = (cg ^ (row & 7)) * 8;
        aSrc[c] = xbf + (size_t)(m0 + row) * CDIM + sc;
    }
    #pragma unroll
    for (int c = 0; c < 2; ++c) {
        int row = c * 32 + srow;
        int sc = (cg ^ (row & 7)) * 8;
        bSrc[c] = wbf + ((size_t)e * OUTD + n0 + row) * CDIM + sc;
    }
    auto stagef = [&](int buf, int k0) {
        #pragma unroll
        for (int c = 0; c < 4; ++c)
            async_copy16(&As[buf][(c * 32 + wave * 8) * BK], aSrc[c] + k0);
        #pragma unroll
        for (int c = 0; c < 2; ++c)
            async_copy16(&Bs[buf][(c * 32 + wave * 8) * BK], bSrc[c] + k0);
    };
    auto compute = [&](int cb) {
        #pragma unroll
        for (int ss = 0; ss < 2; ++ss) {
            bf16x8 af[4], bv[2];
            #pragma unroll
            for (int m = 0; m < 4; ++m) {
                int row = wm * 64 + m * 16 + fr;
                int ch = ((ss * 4 + fq) ^ (row & 7)) * 8;
                af[m] = *(const bf16x8*)(&As[cb][row * BK + ch]);
            }
            #pragma unroll
            for (int nn = 0; nn < 2; ++nn) {
                int row = wn * 32 + nn * 16 + fr;
                int ch = ((ss * 4 + fq) ^ (row & 7)) * 8;
                bv[nn] = *(const bf16x8*)(&Bs[cb][row * BK + ch]);
            }
            #pragma unroll
            for (int m = 0; m < 4; ++m)
                #pragma unroll
                for (int nn = 0; nn < 2; ++nn)
                    acc[m][nn] = __builtin_amdgcn_mfma_f32_16x16x32_bf16(af[m], bv[nn], acc[m][nn], 0, 0, 0);
        }
    };
    stagef(0, 0);
    __syncthreads();
    int cur = 0;
    #pragma unroll
    for (int t = 0; t < 8; ++t) {
        if (t < 7) stagef(cur ^ 1, (t + 1) * BK);
        compute(cur);
        __syncthreads();
        cur ^= 1;
    }
    #pragma unroll
    for (int m = 0; m < 4; ++m)
        #pragma unroll
        for (int q = 0; q < 4; ++q) {
            int r = m0 + wm * 64 + m * 16 + fq * 4 + q;
            float* yrow = y + (size_t)r * OUTD + n0 + wn * 32 + fr;
            #pragma unroll
            for (int nn = 0; nn < 2; ++nn) yrow[nn * 16] += acc[m][nn][q];
        }
}

extern "C" void kernel_launch(void* const* d_in, const int* in_sizes, int n_in,
                              void* d_out, int out_size, void* d_ws, size_t ws_size,
                              hipStream_t stream) {
    const float* x        = (const float*)d_in[0];
    const float* assign_w = (const float*)d_in[1];
    const float* assign_b = (const float*)d_in[2];
    const float* pw_w1    = (const float*)d_in[3];
    const float* bias_w   = (const float*)d_in[4];
    const float* bias_b   = (const float*)d_in[5];
    float* y    = (float*)d_out;                 // [TB*OUTD]
    float* loss = y + (size_t)TB * OUTD;         // [1]

    char* ws = (char*)d_ws;
    unsigned short* xbf  = (unsigned short*)(ws);                 // 16,777,216 B
    unsigned short* wbf  = (unsigned short*)(ws + 16777216);      //  8,912,896 B
    int*    idx0      = (int*)   (ws + 25690112);                 //  1,048,576 B
    int*    idx1      = (int*)   (ws + 26738688);                 //  1,048,576 B
    int*    dec       = (int*)   (ws + 27787264);                 //     65,536 B
    float2* respd     = (float2*)(ws + 27852800);                 //    131,072 B
    int*    flaglist  = (int*)   (ws + 27983872);                 //     32,768 B
    unsigned short* awhl = (unsigned short*)(ws + 28016640);      //     32,768 B
    char*   misc      = ws + 28049408;
    int*    cnt0      = (int*)   (misc + 0);
    int*    cnt1      = (int*)   (misc + 64);
    float*  importance= (float*) (misc + 128);
    int*    nflag     = (int*)   (misc + 192);
    int*    wflag     = (int*)   (misc + 196);
    int*    sn0       = (int*)   (misc + 200);
    int*    sn1       = (int*)   (misc + 204);
    int*    sched0    = (int*)   (misc + 256);
    int*    sched1    = (int*)   (misc + 896);

    k_prep<<<1, 256, 0, stream>>>(assign_w, awhl, cnt0, cnt1, importance, nflag, wflag);
    k_wconv<<<(NE_TOT * OUTD * CDIM / 4 + 255) / 256, 256, 0, stream>>>(pw_w1, bias_w, wbf, wflag);
    k_gate<<<TB / 64, 256, 0, stream>>>(x, awhl, assign_b, xbf, dec, respd,
                                        flaglist, nflag, importance);
    k_repair<<<32, 256, 0, stream>>>(x, assign_w, assign_b, flaglist, nflag,
                                     dec, respd, importance);
    k_build<<<TB / 256, 256, 0, stream>>>(dec, cnt0, cnt1, idx0, idx1);
    k_finish<<<1, 128, 0, stream>>>(importance, loss, cnt0, cnt1, sched0, sched1, sn0, sn1);
    k_gemm<0><<<dim3(OUTD / BN, MAX_SCHED), 256, 0, stream>>>(
        xbf, wbf, cnt0, idx0, respd, sched0, sn0, bias_b, y);
    k_gemm<1><<<dim3(OUTD / BN, MAX_SCHED), 256, 0, stream>>>(
        xbf, wbf, cnt1, idx1, respd, sched1, sn1, bias_b, y);
    k_dense<<<dim3(OUTD / BN, TB / BM), 256, 0, stream>>>(xbf, wbf, wflag, y);
}

// Round 7
// 135.768 us; speedup vs baseline: 1.2687x; 1.0485x over previous
//
#include <hip/hip_runtime.h>
#include <hip/hip_bf16.h>

#define TB 16384
#define CDIM 512
#define OUTD 512
#define NE 16
#define NE_TOT 17
#define LOSS_SCALE 0.01f
#define BM 128
#define BN 64
#define BK 32
#define NSTEP 16
#define MAX_SCHED 144
#define MAXFLAG 8192
#define MARGIN 1e-3f

typedef __bf16 bf16_t;
typedef bf16_t bf16x8 __attribute__((ext_vector_type(8)));
typedef float f32x4 __attribute__((ext_vector_type(4)));
typedef unsigned short ushort4_t __attribute__((ext_vector_type(4)));
typedef unsigned short ushort8_t __attribute__((ext_vector_type(8)));

__device__ __forceinline__ unsigned short f2bf(float f) {
    unsigned int u = __float_as_uint(f);
    u += 0x7fffu + ((u >> 16) & 1u);   // round-to-nearest-even
    return (unsigned short)(u >> 16);
}
__device__ __forceinline__ float bf2f(unsigned short h) {
    return __uint_as_float((unsigned int)h << 16);
}

__device__ __forceinline__ void async_copy16(void* lds, const void* g) {
    __builtin_amdgcn_global_load_lds(
        (const __attribute__((address_space(1))) unsigned int*)g,
        (__attribute__((address_space(3))) unsigned int*)lds, 16, 0, 0);
}

// ---------------- prep: init small state + assign_w hi/lo bf16 split ----------------
__global__ __launch_bounds__(256) void k_prep(
    const float* __restrict__ aw, unsigned short* __restrict__ awhl,
    int* cnt0, int* cnt1, float* importance, int* nflag, int* wflag)
{
    int t = threadIdx.x;
    if (t < NE) { cnt0[t] = 0; cnt1[t] = 0; importance[t] = 0.f; }
    if (t == 0) { *nflag = 0; *wflag = 0; }
    for (int i = t; i < NE * CDIM; i += 256) {
        float f = aw[i];
        unsigned short h = f2bf(f);
        float r = f - bf2f(h);
        awhl[i] = h;
        awhl[NE * CDIM + i] = f2bf(r);
    }
}

// pw_w1 + bias_w -> wbf [17][OUT][C] bf16; also detect bias_w != 0
__global__ void k_wconv(const float* __restrict__ pw, const float* __restrict__ bw,
                        unsigned short* __restrict__ wbf, int* __restrict__ wflag) {
    long i = (long)blockIdx.x * 256 + threadIdx.x;   // float4 index
    const long NPW = (long)NE * OUTD * CDIM / 4;
    const long NTOT = (long)NE_TOT * OUTD * CDIM / 4;
    if (i >= NTOT) return;
    const float* src = (i < NPW) ? (pw + i * 4) : (bw + (i - NPW) * 4);
    float4 v = *(const float4*)src;
    ushort4_t o;
    o[0] = f2bf(v.x); o[1] = f2bf(v.y); o[2] = f2bf(v.z); o[3] = f2bf(v.w);
    *(ushort4_t*)(wbf + i * 4) = o;
    if (i >= NPW && (v.x != 0.f || v.y != 0.f || v.z != 0.f || v.w != 0.f))
        atomicOr(wflag, 1);
}

// ---------------- gating via MFMA hi/lo ----------------
__global__ __launch_bounds__(256) void k_gate(
    const float* __restrict__ x, const unsigned short* __restrict__ awhl,
    const float* __restrict__ ab, unsigned short* __restrict__ xbf,
    int* __restrict__ dec, float2* __restrict__ respd,
    int* __restrict__ flaglist, int* __restrict__ nflag, float* __restrict__ importance)
{
    __shared__ float imp_s[NE];
    int tid = threadIdx.x;
    if (tid < NE) imp_s[tid] = 0.f;
    __syncthreads();

    int wv = tid >> 6, l = tid & 63;
    int n0 = blockIdx.x * 64 + wv * 16;
    int e = l & 15;
    int kg = l >> 4;

    const float* xrow = x + (size_t)(n0 + e) * CDIM + kg * 8;
    unsigned short* xbrow = xbf + (size_t)(n0 + e) * CDIM + kg * 8;
    const unsigned short* whiP = awhl + e * CDIM + kg * 8;
    const unsigned short* wloP = whiP + NE * CDIM;

    f32x4 acc = (f32x4){0.f, 0.f, 0.f, 0.f};
    #pragma unroll 4
    for (int ks = 0; ks < 16; ++ks) {
        float4 v0 = *(const float4*)(xrow + ks * 32);
        float4 v1 = *(const float4*)(xrow + ks * 32 + 4);
        ushort8_t hx, lx;
        #define CVT(idx, f) { unsigned short h_ = f2bf(f); hx[idx] = h_; \
                              float r_ = (f) - bf2f(h_); lx[idx] = f2bf(r_); }
        CVT(0, v0.x) CVT(1, v0.y) CVT(2, v0.z) CVT(3, v0.w)
        CVT(4, v1.x) CVT(5, v1.y) CVT(6, v1.z) CVT(7, v1.w)
        #undef CVT
        *(ushort8_t*)(xbrow + ks * 32) = hx;
        ushort8_t wh8 = *(const ushort8_t*)(whiP + ks * 32);
        ushort8_t wl8 = *(const ushort8_t*)(wloP + ks * 32);
        bf16x8 ah = *(bf16x8*)&hx, al = *(bf16x8*)&lx;
        bf16x8 bh = *(bf16x8*)&wh8, bl = *(bf16x8*)&wl8;
        acc = __builtin_amdgcn_mfma_f32_16x16x32_bf16(al, bh, acc, 0, 0, 0);
        acc = __builtin_amdgcn_mfma_f32_16x16x32_bf16(ah, bl, acc, 0, 0, 0);
        acc = __builtin_amdgcn_mfma_f32_16x16x32_bf16(ah, bh, acc, 0, 0, 0);
    }
    float bias = ab[e];
    f32x4 E;
    #pragma unroll
    for (int q = 0; q < 4; ++q) E[q] = acc[q] + bias;

    f32x4 m1 = E, m2, m3;
    #pragma unroll
    for (int q = 0; q < 4; ++q) { m2[q] = -3.4e38f; m3[q] = -3.4e38f; }
    #pragma unroll
    for (int off = 1; off <= 8; off <<= 1) {
        #pragma unroll
        for (int q = 0; q < 4; ++q) {
            float o1 = __shfl_xor(m1[q], off, 64);
            float o2 = __shfl_xor(m2[q], off, 64);
            float o3 = __shfl_xor(m3[q], off, 64);
            float M1 = fmaxf(m1[q], o1), x1 = fminf(m1[q], o1);
            float h2 = fmaxf(m2[q], o2), l2 = fminf(m2[q], o2);
            float M2 = fmaxf(x1, h2), x2 = fminf(x1, h2);
            float M3 = fmaxf(fmaxf(x2, l2), fmaxf(m3[q], o3));
            m1[q] = M1; m2[q] = M2; m3[q] = M3;
        }
    }
    f32x4 p, z;
    #pragma unroll
    for (int q = 0; q < 4; ++q) p[q] = (E[q] >= m2[q]) ? expf(E[q] - m1[q]) : 0.f;
    z = p;
    #pragma unroll
    for (int off = 1; off <= 8; off <<= 1)
        #pragma unroll
        for (int q = 0; q < 4; ++q) z[q] += __shfl_xor(z[q], off, 64);
    f32x4 resp;
    #pragma unroll
    for (int q = 0; q < 4; ++q) resp[q] = p[q] / z[q];

    int grp = l >> 4;
    int elo_q[4], ehi_q[4];
    float rlo_q[4], rhi_q[4];
    #pragma unroll
    for (int q = 0; q < 4; ++q) {
        unsigned long long mq = __ballot(p[q] > 0.f);
        unsigned int sub = (unsigned int)((mq >> (grp * 16)) & 0xffffULL);
        elo_q[q] = __builtin_ctz(sub);
        ehi_q[q] = 31 - __builtin_clz(sub);
        rlo_q[q] = __shfl(resp[q], grp * 16 + elo_q[q], 64);
        rhi_q[q] = __shfl(resp[q], grp * 16 + ehi_q[q], 64);
    }
    if ((l & 15) == 0) {
        #pragma unroll
        for (int q = 0; q < 4; ++q) {
            int n = n0 + grp * 4 + q;
            dec[n] = elo_q[q] | (ehi_q[q] << 8);
            respd[n] = make_float2(rlo_q[q], rhi_q[q]);
            if (m2[q] - m3[q] < MARGIN) {
                int ix = atomicAdd(nflag, 1);
                if (ix < MAXFLAG) flaglist[ix] = n;
            }
        }
    }
    float s = resp[0] + resp[1] + resp[2] + resp[3];
    s += __shfl_xor(s, 16, 64);
    s += __shfl_xor(s, 32, 64);
    if (l < 16) atomicAdd(&imp_s[e], s);
    __syncthreads();
    if (tid < NE) unsafeAtomicAdd(&importance[tid], imp_s[tid]);
}

// ---------------- fp64 repair for ambiguous tokens ----------------
__global__ __launch_bounds__(256) void k_repair(
    const float* __restrict__ x, const float* __restrict__ aw, const float* __restrict__ ab,
    const int* __restrict__ flaglist, const int* __restrict__ nflag,
    int* __restrict__ dec, float2* __restrict__ respd, float* __restrict__ importance)
{
    __shared__ double part[16][17];
    __shared__ double Ed[16];
    int tid = threadIdx.x;
    int e = tid >> 4, p = tid & 15;
    int nf = *nflag; if (nf > MAXFLAG) nf = MAXFLAG;
    for (int fi = blockIdx.x; fi < nf; fi += gridDim.x) {
        int n = flaglist[fi];
        const float* xp = x + (size_t)n * CDIM + p * 32;
        const float* wp = aw + e * CDIM + p * 32;
        double acc = 0.0;
        for (int j = 0; j < 32; ++j) acc = fma((double)xp[j], (double)wp[j], acc);
        part[e][p] = acc;
        __syncthreads();
        if (tid < 16) {
            double s = (double)ab[tid];
            for (int q = 0; q < 16; ++q) s += part[tid][q];
            Ed[tid] = s;
        }
        __syncthreads();
        if (tid == 0) {
            double m1 = -1e300, m2 = -1e300, m3 = -1e300;
            for (int q = 0; q < 16; ++q) {
                double v = Ed[q];
                if (v > m1) { m3 = m2; m2 = m1; m1 = v; }
                else if (v > m2) { m3 = m2; m2 = v; }
                else if (v > m3) { m3 = v; }
            }
            int elo = -1, ehi = -1;
            for (int q = 0; q < 16; ++q)
                if (Ed[q] >= m2) { if (elo < 0) elo = q; else ehi = q; }
            double plo = exp(Ed[elo] - m1), phi = exp(Ed[ehi] - m1);
            double zz = plo + phi;
            float rlo = (float)(plo / zz), rhi = (float)(phi / zz);
            int od = dec[n]; float2 orr = respd[n];
            unsafeAtomicAdd(&importance[od & 0xff], -orr.x);
            unsafeAtomicAdd(&importance[(od >> 8) & 0xff], -orr.y);
            unsafeAtomicAdd(&importance[elo], rlo);
            unsafeAtomicAdd(&importance[ehi], rhi);
            dec[n] = elo | (ehi << 8);
            respd[n] = make_float2(rlo, rhi);
        }
        __syncthreads();
    }
}

// ---------------- rank-list building ----------------
__global__ __launch_bounds__(256) void k_build(
    const int* __restrict__ dec, int* __restrict__ cnt0, int* __restrict__ cnt1,
    int* __restrict__ idx0, int* __restrict__ idx1)
{
    __shared__ int l0[NE], l1[NE], b0[NE], b1[NE];
    int tid = threadIdx.x;
    if (tid < NE) { l0[tid] = 0; l1[tid] = 0; }
    __syncthreads();
    int n = blockIdx.x * 256 + tid;
    int d = dec[n];
    int elo = d & 0xff, ehi = (d >> 8) & 0xff;
    int p0 = atomicAdd(&l0[elo], 1);
    int p1 = atomicAdd(&l1[ehi], 1);
    __syncthreads();
    if (tid < NE) {
        b0[tid] = atomicAdd(&cnt0[tid], l0[tid]);
        b1[tid] = atomicAdd(&cnt1[tid], l1[tid]);
    }
    __syncthreads();
    idx0[elo * TB + b0[elo] + p0] = n;
    idx1[ehi * TB + b1[ehi] + p1] = n;
}

// ---------------- loss + schedule (fused tail) ----------------
__global__ void k_finish(const float* __restrict__ importance, float* __restrict__ out_loss,
                         const int* __restrict__ cnt0, const int* __restrict__ cnt1,
                         int* __restrict__ sched0, int* __restrict__ sched1,
                         int* __restrict__ sn0, int* __restrict__ sn1) {
    int l = threadIdx.x;
    if (l < 64) {
        float v = (l < NE) ? importance[l] : 0.f;
        float s = v;
        #pragma unroll
        for (int off = 8; off >= 1; off >>= 1) s += __shfl_xor(s, off, 64);
        float mean = s / 16.f;
        float d = (l < NE) ? (v - mean) : 0.f;
        float ss = d * d;
        #pragma unroll
        for (int off = 8; off >= 1; off >>= 1) ss += __shfl_xor(ss, off, 64);
        if (l == 0) {
            float stdv = sqrtf(ss / 15.f);   // ddof=1
            out_loss[0] = LOSS_SCALE * stdv / mean;
        }
    } else if (l == 64) {
        int p = 0;
        for (int e = 0; e < NE; ++e) {
            int nb = (cnt0[e] + BM - 1) / BM;
            for (int i = 0; i < nb; ++i) sched0[p++] = (e << 16) | i;
        }
        *sn0 = p;
    } else if (l == 65) {
        int p = 0;
        for (int e = 0; e < NE; ++e) {
            int nb = (cnt1[e] + BM - 1) / BM;
            for (int i = 0; i < nb; ++i) sched1[p++] = (e << 16) | i;
        }
        *sn1 = p;
    }
}

// ---------------- GEMM: BM=128 BN=64 BK=32, 4-buffer depth-3 counted-vmcnt pipeline.
// MODE 0: rank0 (gather, y = w*acc + bias_b); MODE 1: rank1 (gather, y += w*acc);
// MODE 2: dense bias GEMM (y += acc, gated on wflag).
// grid = (sched, 8); gridDim.x % 8 == 0 so the 8 n-blocks of one tile share an XCD L2.
template<int MODE>
__global__ __launch_bounds__(256) void k_gemm(
    const unsigned short* __restrict__ xbf, const unsigned short* __restrict__ wbf,
    const int* __restrict__ cnts, const int* __restrict__ idx,
    const float2* __restrict__ respd, const int* __restrict__ sched,
    const int* __restrict__ sn, const int* __restrict__ wflag,
    const float* __restrict__ bias_b, float* __restrict__ y)
{
    int e, m0, cnt;
    const int* my_idx = nullptr;
    if (MODE == 2) {
        if (*wflag == 0) return;
        e = NE; m0 = blockIdx.x * BM; cnt = TB;
    } else {
        if ((int)blockIdx.x >= *sn) return;
        int s = sched[blockIdx.x];
        e = s >> 16; m0 = (s & 0xffff) * BM; cnt = cnts[e];
        my_idx = idx + e * TB;
    }
    int n0 = blockIdx.y * BN;
    int tid = threadIdx.x;
    int wave = tid >> 6, lane = tid & 63;
    int wm = wave >> 1, wn = wave & 1;
    int fr = lane & 15, fq = lane >> 4;

    __shared__ unsigned short As[4][BM * BK];   // 32 KiB
    __shared__ unsigned short Bs[4][BN * BK];   // 16 KiB

    f32x4 acc[4][2];
    #pragma unroll
    for (int m = 0; m < 4; ++m)
        #pragma unroll
        for (int nn = 0; nn < 2; ++nn) acc[m][nn] = (f32x4){0.f, 0.f, 0.f, 0.f};

    // staging: per wave 3 gload_lds/tile. Granule = 16 rows x 64B: lane l ->
    // row rl=l>>2, chunk cc=l&3. Source pre-swizzled (cc ^ rl&3) so linear LDS
    // dest + swizzled ds_read match (rule #21); residual 2-way alias is free (m136).
    int rl = lane >> 2, cc = lane & 3;
    int swz = (cc ^ (rl & 3)) * 8;             // element offset within 32-elem K tile
    int rowA0 = wave * 32 + rl;
    int rowA1 = rowA0 + 16;
    int tok0, tok1;
    if (MODE == 2) { tok0 = m0 + rowA0; tok1 = m0 + rowA1; }
    else {
        int rr0 = m0 + rowA0; if (rr0 >= cnt) rr0 = cnt - 1;
        int rr1 = m0 + rowA1; if (rr1 >= cnt) rr1 = cnt - 1;
        tok0 = my_idx[rr0]; tok1 = my_idx[rr1];
    }
    const unsigned short* aS0 = xbf + (size_t)tok0 * CDIM + swz;
    const unsigned short* aS1 = xbf + (size_t)tok1 * CDIM + swz;
    const unsigned short* bS0 = wbf + ((size_t)e * OUTD + n0 + wave * 16 + rl) * CDIM + swz;

    unsigned short* dA0 = &As[0][(wave * 32) * BK];
    unsigned short* dA1 = &As[0][(wave * 32 + 16) * BK];
    unsigned short* dB0 = &Bs[0][(wave * 16) * BK];
    const int ASTRIDE = BM * BK, BSTRIDE = BN * BK;

    auto stage = [&](int buf, int t) {
        async_copy16(dA0 + buf * ASTRIDE, aS0 + t * BK);
        async_copy16(dA1 + buf * ASTRIDE, aS1 + t * BK);
        async_copy16(dB0 + buf * BSTRIDE, bS0 + t * BK);
    };
    auto compute = [&](int cb) {
        bf16x8 af[4], bv[2];
        #pragma unroll
        for (int m = 0; m < 4; ++m) {
            int row = wm * 64 + m * 16 + fr;
            af[m] = *(const bf16x8*)(&As[cb][row * BK + ((fq ^ (row & 3)) * 8)]);
        }
        #pragma unroll
        for (int nn = 0; nn < 2; ++nn) {
            int row = wn * 32 + nn * 16 + fr;
            bv[nn] = *(const bf16x8*)(&Bs[cb][row * BK + ((fq ^ (row & 3)) * 8)]);
        }
        #pragma unroll
        for (int m = 0; m < 4; ++m)
            #pragma unroll
            for (int nn = 0; nn < 2; ++nn)
                acc[m][nn] = __builtin_amdgcn_mfma_f32_16x16x32_bf16(af[m], bv[nn], acc[m][nn], 0, 0, 0);
    };

    // prologue: 3 tiles in flight (9 loads/wave)
    stage(0, 0); stage(1, 1); stage(2, 2);
    #pragma unroll
    for (int t = 0; t < NSTEP; ++t) {
        // wait until tile t's 3 loads done; keep tiles t+1,t+2 in flight (T4: never drain to 0)
        if (t <= NSTEP - 3)      asm volatile("s_waitcnt vmcnt(6)" ::: "memory");
        else if (t == NSTEP - 2) asm volatile("s_waitcnt vmcnt(3)" ::: "memory");
        else                     asm volatile("s_waitcnt vmcnt(0)" ::: "memory");
        __builtin_amdgcn_sched_barrier(0);
        __builtin_amdgcn_s_barrier();
        compute(t & 3);
        if (t <= NSTEP - 4) stage((t + 3) & 3, t + 3);
    }

    float bb[2];
    if (MODE == 0) {
        #pragma unroll
        for (int nn = 0; nn < 2; ++nn) bb[nn] = bias_b[n0 + wn * 32 + nn * 16 + fr];
    }
    #pragma unroll
    for (int m = 0; m < 4; ++m)
        #pragma unroll
        for (int q = 0; q < 4; ++q) {
            int r = m0 + wm * 64 + m * 16 + fq * 4 + q;
            if (r < cnt) {
                float* yrow;
                float w = 1.f;
                if (MODE == 2) {
                    yrow = y + (size_t)r * OUTD + n0 + wn * 32 + fr;
                } else {
                    int tok = my_idx[r];
                    float2 rp = respd[tok];
                    w = (MODE == 0) ? rp.x : rp.y;
                    yrow = y + (size_t)tok * OUTD + n0 + wn * 32 + fr;
                }
                #pragma unroll
                for (int nn = 0; nn < 2; ++nn) {
                    if (MODE == 0) yrow[nn * 16] = fmaf(w, acc[m][nn][q], bb[nn]);
                    else if (MODE == 1) yrow[nn * 16] += w * acc[m][nn][q];
                    else yrow[nn * 16] += acc[m][nn][q];
                }
            }
        }
}

extern "C" void kernel_launch(void* const* d_in, const int* in_sizes, int n_in,
                              void* d_out, int out_size, void* d_ws, size_t ws_size,
                              hipStream_t stream) {
    const float* x        = (const float*)d_in[0];
    const float* assign_w = (const float*)d_in[1];
    const float* assign_b = (const float*)d_in[2];
    const float* pw_w1    = (const float*)d_in[3];
    const float* bias_w   = (const float*)d_in[4];
    const float* bias_b   = (const float*)d_in[5];
    float* y    = (float*)d_out;                 // [TB*OUTD]
    float* loss = y + (size_t)TB * OUTD;         // [1]

    char* ws = (char*)d_ws;
    unsigned short* xbf  = (unsigned short*)(ws);                 // 16,777,216 B
    unsigned short* wbf  = (unsigned short*)(ws + 16777216);      //  8,912,896 B
    int*    idx0      = (int*)   (ws + 25690112);                 //  1,048,576 B
    int*    idx1      = (int*)   (ws + 26738688);                 //  1,048,576 B
    int*    dec       = (int*)   (ws + 27787264);                 //     65,536 B
    float2* respd     = (float2*)(ws + 27852800);                 //    131,072 B
    int*    flaglist  = (int*)   (ws + 27983872);                 //     32,768 B
    unsigned short* awhl = (unsigned short*)(ws + 28016640);      //     32,768 B
    char*   misc      = ws + 28049408;
    int*    cnt0      = (int*)   (misc + 0);
    int*    cnt1      = (int*)   (misc + 64);
    float*  importance= (float*) (misc + 128);
    int*    nflag     = (int*)   (misc + 192);
    int*    wflag     = (int*)   (misc + 196);
    int*    sn0       = (int*)   (misc + 200);
    int*    sn1       = (int*)   (misc + 204);
    int*    sched0    = (int*)   (misc + 256);
    int*    sched1    = (int*)   (misc + 896);

    k_prep<<<1, 256, 0, stream>>>(assign_w, awhl, cnt0, cnt1, importance, nflag, wflag);
    k_wconv<<<(NE_TOT * OUTD * CDIM / 4 + 255) / 256, 256, 0, stream>>>(pw_w1, bias_w, wbf, wflag);
    k_gate<<<TB / 64, 256, 0, stream>>>(x, awhl, assign_b, xbf, dec, respd,
                                        flaglist, nflag, importance);
    k_repair<<<32, 256, 0, stream>>>(x, assign_w, assign_b, flaglist, nflag,
                                     dec, respd, importance);
    k_build<<<TB / 256, 256, 0, stream>>>(dec, cnt0, cnt1, idx0, idx1);
    k_finish<<<1, 128, 0, stream>>>(importance, loss, cnt0, cnt1, sched0, sched1, sn0, sn1);
    k_gemm<0><<<dim3(MAX_SCHED, OUTD / BN), 256, 0, stream>>>(
        xbf, wbf, cnt0, idx0, respd, sched0, sn0, wflag, bias_b, y);
    k_gemm<1><<<dim3(MAX_SCHED, OUTD / BN), 256, 0, stream>>>(
        xbf, wbf, cnt1, idx1, respd, sched1, sn1, wflag, bias_b, y);
    k_gemm<2><<<dim3(TB / BM, OUTD / BN), 256, 0, stream>>>(
        xbf, wbf, cnt0, idx0, respd, sched0, sn0, wflag, bias_b, y);
}